// Round 20
// baseline (30.156 us; speedup 1.0000x reference)
//
#include <hip/hip_runtime.h>

#define E  9
#define B_ 8
#define H_ 224
#define W_ 224
#define C_ 32
#define TH 4                        // rows per thread
#define TW 2                        // w pixels per thread
#define CPT 2                       // channels per thread
#define WT 32                       // w pixels per block (16 w-groups x 2)
#define STRIPS (H_ / TH)            // 56
#define WTILES (W_ / WT)            // 7
#define NBLK (B_ * STRIPS * WTILES) // 3136 = 12.25 blocks/CU, %8==0

typedef float v2f __attribute__((ext_vector_type(2)));

__global__ __launch_bounds__(256) void fm_main(const float* __restrict__ inp,
                                               const float* __restrict__ kern,
                                               const float* __restrict__ mask,
                                               float* __restrict__ out) {
    int t = threadIdx.x;

    // Bijective XCD-chunk swizzle (392 blocks per XCD).
    int bid = blockIdx.x;
    int swz = (bid & 7) * (NBLK / 8) + (bid >> 3);
    int bw  = swz % WTILES;
    int t2  = swz / WTILES;
    int hs  = (t2 % STRIPS) * TH;   // strip start row
    int b   = t2 / STRIPS;

    int c  = (t & 15) << 1;         // channel pair: 0,2,...,30 (lane-contiguous)
    int wg = t >> 4;                // 0..15 -> w-pair
    int w0 = bw * WT + wg * TW;     // first of 2 owned w positions

    const float* base = inp + (((size_t)b * H_ * W_ + w0) * C_) + c;
    bool wm = (w0 > 0);             // col w0-1 exists
    bool wp = (w0 + TW < W_);       // col w0+2 exists

    // ---- Tap prologue: (TH+2) x (TW+2) v2f taps -> 48 registers.
    // dwordx2 loads move 512B/wave-instr: loads/elem 2.57 -> 1.5,
    // stores 1 -> 0.5 (the R11 2ch idea, deconfounded by e-outer coeffs).
    v2f tap[TH + 2][TW + 2];
#pragma unroll
    for (int r = 0; r < TH + 2; ++r) {
        int hh = hs - 1 + r;
        if ((unsigned)hh < (unsigned)H_) {   // block-uniform branch
            const float* p = base + (size_t)hh * (W_ * C_);
            tap[r][0] = wm ? *reinterpret_cast<const v2f*>(p - C_)
                           : (v2f){0.f, 0.f};
            tap[r][1] = *reinterpret_cast<const v2f*>(p);
            tap[r][2] = *reinterpret_cast<const v2f*>(p + C_);
            tap[r][3] = wp ? *reinterpret_cast<const v2f*>(p + 2 * C_)
                           : (v2f){0.f, 0.f};
        } else {
#pragma unroll
            for (int j = 0; j < TW + 2; ++j) tap[r][j] = (v2f){0.f, 0.f};
        }
    }

    // ---- absmax(|mask|): 16 lanes (ch pairs) cover all 32 channels.
    v2f mv[E];
    float mx = 0.f;
#pragma unroll
    for (int e = 0; e < E; ++e) {
        v2f m = *reinterpret_cast<const v2f*>(mask + e * C_ + c);
        mv[e].x = fabsf(m.x); mv[e].y = fabsf(m.y);
        mx = fmaxf(mx, fmaxf(mv[e].x, mv[e].y));
    }
    mx = fmaxf(mx, __shfl_xor(mx, 1));
    mx = fmaxf(mx, __shfl_xor(mx, 2));
    mx = fmaxf(mx, __shfl_xor(mx, 4));
    mx = fmaxf(mx, __shfl_xor(mx, 8));
    float inv = 1.f / (mx + 1e-6f);

    v2f cm[E], ck[E];
#pragma unroll
    for (int e = 0; e < E; ++e) {
        cm[e].x = mv[e].x * inv;
        cm[e].y = mv[e].y * inv;
        ck[e] = *reinterpret_cast<const v2f*>(kern + e * C_ + c);
    }

    // tap order: e=0 center, then (y,x) raster skipping center
    const int dyA[E] = {0, -1, -1, -1, 0, 0, 1, 1, 1};
    const int dxA[E] = {0, -1,  0,  1, -1, 1, -1, 0, 1};

    const float inv9 = 1.f / 9.f;

    float n0[TH][TW], n1[TH][TW], s0[TH][TW], s1[TH][TW];
#pragma unroll
    for (int s = 0; s < TH; ++s)
#pragma unroll
        for (int j = 0; j < TW; ++j) {
            n0[s][j] = 0.f; n1[s][j] = 0.f;
            s0[s][j] = 0.f; s1[s][j] = 0.f;
        }

    // ---- Pass 1: e-outer, accumulate n and sum (no d storage).
#pragma unroll
    for (int e = 0; e < E; ++e) {
        v2f m = cm[e], k = ck[e];
#pragma unroll
        for (int s = 0; s < TH; ++s) {
#pragma unroll
            for (int j = 0; j < TW; ++j) {
                v2f tp = tap[s + 1 + dyA[e]][1 + j + dxA[e]];
                float dx = fmaf(tp.x, m.x, -k.x);
                float dy = fmaf(tp.y, m.y, -k.y);
                n0[s][j] += fabsf(dx);   // abs as src modifier
                n1[s][j] += fabsf(dy);
                s0[s][j] += dx;
                s1[s][j] += dy;
            }
        }
    }

    // ---- Pass 2: recompute d from resident taps; finalize and store.
#pragma unroll
    for (int s = 0; s < TH; ++s) {
#pragma unroll
        for (int j = 0; j < TW; ++j) {
            float nmx = s0[s][j] * (-inv9);
            float nmy = s1[s][j] * (-inv9);
            float vx = 0.f, vy = 0.f;
#pragma unroll
            for (int e = 0; e < E; ++e) {
                v2f tp = tap[s + 1 + dyA[e]][1 + j + dxA[e]];
                float dx = fmaf(tp.x, cm[e].x, -ck[e].x);
                float dy = fmaf(tp.y, cm[e].y, -ck[e].y);
                vx += fabsf(fabsf(dx) + nmx);
                vy += fabsf(fabsf(dy) + nmy);
            }
            v2f o;
            o.x = fmaf(vx, -inv9, 1.f) * fmaf(n0[s][j], -inv9, 1.f);
            o.y = fmaf(vy, -inv9, 1.f) * fmaf(n1[s][j], -inv9, 1.f);

            // write-once/never-read: non-temporal bypasses L2/L3
            float* op = out + (((size_t)b * H_ + (hs + s)) * W_ + (w0 + j)) * C_ + c;
            __builtin_nontemporal_store(o, reinterpret_cast<v2f*>(op));
        }
    }
}

extern "C" void kernel_launch(void* const* d_in, const int* in_sizes, int n_in,
                              void* d_out, int out_size, void* d_ws, size_t ws_size,
                              hipStream_t stream) {
    const float* inp  = (const float*)d_in[0];
    const float* kern = (const float*)d_in[1];
    const float* mask = (const float*)d_in[2];
    float* out = (float*)d_out;

    fm_main<<<NBLK, 256, 0, stream>>>(inp, kern, mask, out);
}

// Round 21
// 25.237 us; speedup vs baseline: 1.1949x; 1.1949x over previous
//
#include <hip/hip_runtime.h>

#define E  9
#define B_ 8
#define H_ 224
#define W_ 224
#define C_ 32
#define TH 7                        // rows per sub-strip
#define NSUB 2                      // sub-strips per thread (14 rows total)
#define TW 2                        // w pixels per thread
#define WT 16                       // w pixels per block (8 w-pairs x 32 ch)
#define STRIPS (H_ / (TH * NSUB))   // 16
#define WTILES (W_ / WT)            // 14
#define NBLK (B_ * STRIPS * WTILES) // 1792 = 7 blocks/CU, %8==0

__global__ __launch_bounds__(256) void fm_main(const float* __restrict__ inp,
                                               const float* __restrict__ kern,
                                               const float* __restrict__ mask,
                                               float* __restrict__ out) {
    int t = threadIdx.x;

    // Bijective XCD-chunk swizzle (224 blocks per XCD).
    int bid = blockIdx.x;
    int swz = (bid & 7) * (NBLK / 8) + (bid >> 3);
    int bw  = swz % WTILES;
    int t2  = swz / WTILES;
    int hs  = (t2 % STRIPS) * (TH * NSUB);   // 14-row strip start
    int b   = t2 / STRIPS;

    int c  = t & 31;                // channel (lane-contiguous -> coalesced)
    int wg = t >> 5;                // 0..7 -> w-pair
    int w0 = bw * WT + wg * TW;     // first of 2 owned w positions

    const float* base = inp + (((size_t)b * H_ * W_ + w0) * C_) + c;
    bool wm = (w0 > 0);             // col w0-1 exists
    bool wp = (w0 + TW < W_);       // col w0+2 exists

    // ---- absmax(|mask|): lanes 0..31 cover all 32 channels. Amortized over
    // 28 outputs now (was 14 in R17) -> prologue cost/elem halves.
    float mv[E];
    float mx = 0.f;
#pragma unroll
    for (int e = 0; e < E; ++e) {
        mv[e] = fabsf(mask[e * C_ + c]);
        mx = fmaxf(mx, mv[e]);
    }
    mx = fmaxf(mx, __shfl_xor(mx, 1));
    mx = fmaxf(mx, __shfl_xor(mx, 2));
    mx = fmaxf(mx, __shfl_xor(mx, 4));
    mx = fmaxf(mx, __shfl_xor(mx, 8));
    mx = fmaxf(mx, __shfl_xor(mx, 16));
    float inv = 1.f / (mx + 1e-6f);

    float cm[E], ck[E];
#pragma unroll
    for (int e = 0; e < E; ++e) {
        cm[e] = mv[e] * inv;
        ck[e] = kern[e * C_ + c];
    }

    // tap order: e=0 center, then (y,x) raster skipping center
    const int dyA[E] = {0, -1, -1, -1, 0, 0, 1, 1, 1};
    const int dxA[E] = {0, -1,  0,  1, -1, 1, -1, 0, 1};

    const float inv9 = 1.f / 9.f;

    // tap[r][j]: tap row (row_base-1+r), col (w0-1+j). Live: 36 regs.
    float tap[TH + 2][TW + 2];

    auto ldrow = [&](int hh, float* r) {
        if ((unsigned)hh < (unsigned)H_) {   // block-uniform branch
            const float* p = base + (size_t)hh * (W_ * C_);
            r[0] = wm ? p[-C_] : 0.f;
            r[1] = p[0];
            r[2] = p[C_];                    // w0+1 < W_ always (output col)
            r[3] = wp ? p[2 * C_] : 0.f;
        } else {
            r[0] = 0.f; r[1] = 0.f; r[2] = 0.f; r[3] = 0.f;
        }
    };

    // e-outer passes over one 7-row sub-strip starting at output row rb.
    auto process = [&](int rb) {
        float n[TH][TW], sm[TH][TW];
#pragma unroll
        for (int s = 0; s < TH; ++s)
#pragma unroll
            for (int j = 0; j < TW; ++j) { n[s][j] = 0.f; sm[s][j] = 0.f; }

        // Pass 1: e-outer, accumulate n and sum (no d storage).
#pragma unroll
        for (int e = 0; e < E; ++e) {
            float m = cm[e], k = ck[e];
#pragma unroll
            for (int s = 0; s < TH; ++s) {
#pragma unroll
                for (int j = 0; j < TW; ++j) {
                    float d0 = fmaf(tap[s + 1 + dyA[e]][1 + j + dxA[e]], m, -k);
                    n[s][j]  += fabsf(d0);   // abs as src modifier
                    sm[s][j] += d0;
                }
            }
        }

        // Pass 2: recompute d from resident taps; finalize and store.
#pragma unroll
        for (int s = 0; s < TH; ++s) {
#pragma unroll
            for (int j = 0; j < TW; ++j) {
                float nm = sm[s][j] * (-inv9);
                float v = 0.f;
#pragma unroll
                for (int e = 0; e < E; ++e) {
                    float d0 = fmaf(tap[s + 1 + dyA[e]][1 + j + dxA[e]],
                                    cm[e], -ck[e]);
                    v += fabsf(fabsf(d0) + nm);
                }
                float o = fmaf(v, -inv9, 1.f) * fmaf(n[s][j], -inv9, 1.f);

                // write-once/never-read: non-temporal bypasses L2/L3
                float* op = out + (((size_t)b * H_ + (rb + s)) * W_ + (w0 + j)) * C_ + c;
                __builtin_nontemporal_store(o, op);
            }
        }
    };

    // ---- Sub-strip A: tap rows hs-1 .. hs+7
#pragma unroll
    for (int r = 0; r < TH + 2; ++r)
        ldrow(hs - 1 + r, tap[r]);
    process(hs);

    // ---- Shift boundary rows (hs+6, hs+7): A's tap[7],tap[8] are B's halo.
#pragma unroll
    for (int j = 0; j < TW + 2; ++j) {
        tap[0][j] = tap[TH][j];
        tap[1][j] = tap[TH + 1][j];
    }
    // Load B's remaining tap rows hs+8 .. hs+14 (7 rows, was 9).
#pragma unroll
    for (int r = 2; r < TH + 2; ++r)
        ldrow(hs + 6 + r, tap[r]);
    process(hs + TH);
}

extern "C" void kernel_launch(void* const* d_in, const int* in_sizes, int n_in,
                              void* d_out, int out_size, void* d_ws, size_t ws_size,
                              hipStream_t stream) {
    const float* inp  = (const float*)d_in[0];
    const float* kern = (const float*)d_in[1];
    const float* mask = (const float*)d_in[2];
    float* out = (float*)d_out;

    fm_main<<<NBLK, 256, 0, stream>>>(inp, kern, mask, out);
}